// Round 1
// baseline (1882.890 us; speedup 1.0000x reference)
//
#include <hip/hip_runtime.h>
#include <hip/hip_bf16.h>

#define Bn 256
#define Sn 1024
#define Hn 256
#define Vn 128
#define En 128

// ---------- Kernel A: T2[v][h] = sum_e emb[v,e]*W_ih[h,e] + b_ih[h] + b_hh[h]
__global__ void k_table(const float* __restrict__ emb, const float* __restrict__ W_ih,
                        const float* __restrict__ b_ih, const float* __restrict__ b_hh,
                        float* __restrict__ T2) {
  int v = blockIdx.x;   // 128
  int h = threadIdx.x;  // 256
  const float* er = emb + v * En;
  const float* wr = W_ih + h * En;
  float acc = 0.f;
  #pragma unroll 8
  for (int e = 0; e < En; ++e) acc = fmaf(er[e], wr[e], acc);
  T2[v * Hn + h] = acc + b_ih[h] + b_hh[h];
}

// ---------- Kernel B: recurrence. 256 blocks (1 batch each), 1024 threads (16 waves).
// Wave w: kseg = w>>2 (k-range 64*kseg..+63), hseg = w&3 (h_out = 64*hseg + lane).
// Each thread holds 64 W_hh weights in VGPRs; h chunk per-lane; h[k] extracted with
// v_readlane -> SGPR -> v_fmac. Partial k-sums reduced via 4KB LDS, tanh, repeat.
__global__ __launch_bounds__(1024) void k_rnn(const int* __restrict__ inp,
    const float* __restrict__ hidden, const float* __restrict__ W_hh,
    const float* __restrict__ T2, float* out_base) {
  __shared__ float T2l[Vn * Hn];   // 128 KB
  __shared__ float part[4 * Hn];   // 4 KB
  __shared__ float hbuf[Hn];       // 1 KB
  __shared__ int   idxl[Sn];       // 4 KB

  const int b = blockIdx.x;
  const int tid = threadIdx.x;
  const int l = tid & 63;
  const int w = tid >> 6;
  const int kseg = w >> 2;
  const int hseg = w & 3;
  const int h_out = (hseg << 6) | l;
  const int k0 = kseg << 6;

  // Stage T2 into LDS (coalesced float4)
  {
    const float4* src = (const float4*)T2;
    float4* dst = (float4*)T2l;
    #pragma unroll
    for (int i = 0; i < 8; ++i) dst[tid + (i << 10)] = src[tid + (i << 10)];
  }
  idxl[tid] = inp[b * Sn + tid];

  // Weight-stationary: W_hh[h_out][k0 .. k0+63] in VGPRs
  float wreg[64];
  {
    const float4* wsrc = (const float4*)(W_hh + h_out * Hn + k0);
    #pragma unroll
    for (int i = 0; i < 16; ++i) {
      float4 t4 = wsrc[i];
      wreg[4*i+0] = t4.x; wreg[4*i+1] = t4.y; wreg[4*i+2] = t4.z; wreg[4*i+3] = t4.w;
    }
  }
  float hreg = hidden[b * Hn + k0 + l];
  __syncthreads();

  __hip_bfloat16* hall = (__hip_bfloat16*)out_base;       // bf16 H_all overlay on outputs region
  float* hfin = out_base + (size_t)Bn * Sn * Vn;          // h_final region

  #pragma unroll 1
  for (int t = 0; t < Sn; ++t) {
    // prefetch x_t (independent of recurrence) -- latency hidden under FMA phase
    float x = 0.f;
    if (tid < Hn) x = T2l[(idxl[t] << 8) | tid];

    const int hbits = __float_as_int(hreg);
    float a0 = 0.f, a1 = 0.f, a2 = 0.f, a3 = 0.f;
    #pragma unroll
    for (int j = 0; j < 64; j += 4) {
      a0 = fmaf(wreg[j+0], __int_as_float(__builtin_amdgcn_readlane(hbits, j+0)), a0);
      a1 = fmaf(wreg[j+1], __int_as_float(__builtin_amdgcn_readlane(hbits, j+1)), a1);
      a2 = fmaf(wreg[j+2], __int_as_float(__builtin_amdgcn_readlane(hbits, j+2)), a2);
      a3 = fmaf(wreg[j+3], __int_as_float(__builtin_amdgcn_readlane(hbits, j+3)), a3);
    }
    part[(kseg << 8) | h_out] = (a0 + a1) + (a2 + a3);
    __syncthreads();

    if (tid < Hn) {
      float ssum = (part[tid] + part[256 + tid]) + (part[512 + tid] + part[768 + tid]);
      float z = x + ssum;
      // tanh(z) = 1 - 2/(exp2(z*2*log2e)+1)
      float e2 = __builtin_amdgcn_exp2f(z * 2.885390081777927f);
      float hn = fmaf(-2.f, __builtin_amdgcn_rcpf(e2 + 1.f), 1.f);
      hbuf[tid] = hn;
      hall[((size_t)(b * Sn + t) << 8) | tid] = __float2bfloat16(hn);
    }
    __syncthreads();
    hreg = hbuf[k0 + l];
  }
  if (tid < Hn) hfin[b * Hn + tid] = hbuf[tid];
}

// ---------- Kernel C: outputs[m, 0:128] = Hall[m, 0:256] @ W_ho^T + b_ho, in place over d_out.
// Block: 64 m-rows, 512 threads (8 waves). lane = m-row; wave w covers v in [16w, 16w+16).
// Hall tile staged bf16 in LDS (padded rows: 258 bf16 -> stride 129 dwords, conflict-free).
// W_ho row chunks are wave-uniform -> scalar loads feeding v_fmac s-operand.
__global__ __launch_bounds__(512) void k_out(const float* __restrict__ W_ho,
    const float* __restrict__ b_ho, float* out_base) {
  __shared__ unsigned int At[64 * 129];  // 33 KB
  const int tid = threadIdx.x;
  const int l = tid & 63;
  const int w = tid >> 6;
  const int vbase = w << 4;
  const size_t m0 = (size_t)blockIdx.x << 6;

  {
    const uint4* src = (const uint4*)((const __hip_bfloat16*)out_base + m0 * Hn);
    #pragma unroll
    for (int i = 0; i < 8; ++i) {
      int g = tid + (i << 9);          // uint4 index 0..4095
      uint4 d = src[g];
      int row = g >> 5;                // 32 uint4 per 256-bf16 row
      int c4 = (g & 31) << 2;          // dword col
      unsigned int* dst = &At[row * 129 + c4];
      dst[0] = d.x; dst[1] = d.y; dst[2] = d.z; dst[3] = d.w;
    }
  }
  __syncthreads();

  float acc[16];
  #pragma unroll
  for (int i = 0; i < 16; ++i) acc[i] = b_ho[vbase + i];

  #pragma unroll 1
  for (int kc = 0; kc < 16; ++kc) {
    float a[16];
    #pragma unroll
    for (int i = 0; i < 8; ++i) {
      unsigned int u = At[l * 129 + (kc << 3) + i];
      a[2*i+0] = __uint_as_float(u << 16);          // bf16 -> f32
      a[2*i+1] = __uint_as_float(u & 0xFFFF0000u);
    }
    #pragma unroll
    for (int vi = 0; vi < 16; ++vi) {
      const float* wrow = W_ho + (vbase + vi) * Hn + (kc << 4);  // wave-uniform -> s_load
      #pragma unroll
      for (int k = 0; k < 16; ++k) acc[vi] = fmaf(a[k], wrow[k], acc[vi]);
    }
  }

  float* orow = out_base + ((m0 + l) << 7) + vbase;
  #pragma unroll
  for (int i = 0; i < 4; ++i) {
    ((float4*)orow)[i] = make_float4(acc[4*i], acc[4*i+1], acc[4*i+2], acc[4*i+3]);
  }
}

extern "C" void kernel_launch(void* const* d_in, const int* in_sizes, int n_in,
                              void* d_out, int out_size, void* d_ws, size_t ws_size,
                              hipStream_t stream) {
  (void)in_sizes; (void)n_in; (void)out_size;
  const int*   inp    = (const int*)  d_in[0];
  const float* hidden = (const float*)d_in[1];
  const float* emb    = (const float*)d_in[2];
  const float* W_ih   = (const float*)d_in[3];
  const float* b_ih   = (const float*)d_in[4];
  const float* W_hh   = (const float*)d_in[5];
  const float* b_hh   = (const float*)d_in[6];
  const float* W_ho   = (const float*)d_in[7];
  const float* b_ho   = (const float*)d_in[8];
  float* out = (float*)d_out;

  // T2 table: prefer d_ws; fallback to the h_final tail (overwritten only at the very end).
  float* T2 = (ws_size >= (size_t)(Vn * Hn * sizeof(float))) ? (float*)d_ws
            : out + (size_t)Bn * Sn * Vn;

  k_table<<<dim3(Vn), dim3(Hn), 0, stream>>>(emb, W_ih, b_ih, b_hh, T2);
  k_rnn<<<dim3(Bn), dim3(1024), 0, stream>>>(inp, hidden, W_hh, T2, out);
  k_out<<<dim3((Bn * Sn) / 64), dim3(512), 0, stream>>>(W_ho, b_ho, out);
}

// Round 2
// 1036.539 us; speedup vs baseline: 1.8165x; 1.8165x over previous
//
#include <hip/hip_runtime.h>
#include <hip/hip_bf16.h>
#include <hip/hip_fp16.h>

#define Bn 256
#define Sn 1024
#define Hn 256
#define Vn 128
#define En 128

typedef _Float16 f16x8 __attribute__((ext_vector_type(8)));
typedef float f32x4 __attribute__((ext_vector_type(4)));

// ---------- Kernel A: T2[v][h] = sum_e emb[v,e]*W_ih[h,e] + b_ih[h] + b_hh[h]
__global__ void k_table(const float* __restrict__ emb, const float* __restrict__ W_ih,
                        const float* __restrict__ b_ih, const float* __restrict__ b_hh,
                        float* __restrict__ T2) {
  int v = blockIdx.x;   // 128
  int h = threadIdx.x;  // 256
  const float* er = emb + v * En;
  const float* wr = W_ih + h * En;
  float acc = 0.f;
  #pragma unroll 8
  for (int e = 0; e < En; ++e) acc = fmaf(er[e], wr[e], acc);
  T2[v * Hn + h] = acc + b_ih[h] + b_hh[h];
}

// ---------- Kernel B: recurrence. 256 blocks (1 batch), 1024 threads (16 waves).
// Wave w owns k in [16w,16w+16). Lane l computes h_out in {l,64+l,128+l,192+l}.
// 16 readlanes broadcast h[16w+j]; 64 fp32 FMAs; partials P[c][h] in LDS
// (double-buffered -> ONE barrier/step); each lane redundantly reduces its own
// next-h (4 LDS reads + shfl_xor butterfly), tanh in-register.
__global__ __launch_bounds__(1024) void k_rnn(const int* __restrict__ inp,
    const float* __restrict__ hidden, const float* __restrict__ W_hh,
    const float* __restrict__ T2, float* out_base) {
  __shared__ _Float16 T2l[Vn * Hn];   // 64 KB (f16: x values are tiny, rounding ~1e-5)
  __shared__ float P[2][16][259];     // ~32 KB partials, pad 259 for banks
  __shared__ int idxl[Sn];            // 4 KB

  const int b = blockIdx.x;
  const int tid = threadIdx.x;
  const int l = tid & 63;
  const int w = tid >> 6;
  const int hsel = (w << 4) | (l & 15);  // the h this lane finalizes
  const int q = l >> 4;                  // quarter (redundancy group)

  // stage T2 -> f16 LDS (coalesced)
  {
    const float4* src = (const float4*)T2;
    #pragma unroll
    for (int i = 0; i < 8; ++i) {
      int g = tid + (i << 10);
      float4 v4 = src[g];
      union { _Float16 h[4]; short4 s; } u;
      u.h[0] = (_Float16)v4.x; u.h[1] = (_Float16)v4.y;
      u.h[2] = (_Float16)v4.z; u.h[3] = (_Float16)v4.w;
      ((short4*)T2l)[g] = u.s;
    }
  }
  idxl[tid] = inp[b * Sn + tid];

  // weight-stationary: wv[r][j] = W_hh[64r + l][16w + j]
  float wv[4][16];
  #pragma unroll
  for (int r = 0; r < 4; ++r) {
    const float4* ws = (const float4*)(W_hh + ((r << 6) | l) * Hn + (w << 4));
    #pragma unroll
    for (int i = 0; i < 4; ++i) {
      float4 t4 = ws[i];
      wv[r][4*i+0] = t4.x; wv[r][4*i+1] = t4.y; wv[r][4*i+2] = t4.z; wv[r][4*i+3] = t4.w;
    }
  }
  float hreg = hidden[b * Hn + hsel];
  __syncthreads();

  _Float16* hall = (_Float16*)out_base;                 // f16 H_all overlay on outputs
  const size_t rowbase = ((size_t)b * Sn) << 8;         // in halves
  float* hfin = out_base + ((size_t)Bn * Sn * Vn);

  #pragma unroll 1
  for (int t = 0; t < Sn; ++t) {
    // pin weights into VGPRs (defeat AGPR homing -> avoid accvgpr_read per FMA)
    #pragma unroll
    for (int r = 0; r < 4; ++r)
      asm volatile("" : "+v"(wv[r][0]), "+v"(wv[r][1]), "+v"(wv[r][2]), "+v"(wv[r][3]),
                        "+v"(wv[r][4]), "+v"(wv[r][5]), "+v"(wv[r][6]), "+v"(wv[r][7]),
                        "+v"(wv[r][8]), "+v"(wv[r][9]), "+v"(wv[r][10]), "+v"(wv[r][11]),
                        "+v"(wv[r][12]), "+v"(wv[r][13]), "+v"(wv[r][14]), "+v"(wv[r][15]));

    float x = (float)T2l[(idxl[t] << 8) | hsel];  // issued early, hides under FMAs
    const int hb = __float_as_int(hreg);
    float a0 = 0.f, a1 = 0.f, a2 = 0.f, a3 = 0.f;
    #pragma unroll
    for (int j = 0; j < 16; ++j) {
      float hs = __int_as_float(__builtin_amdgcn_readlane(hb, j));  // h[16w+j]
      a0 = fmaf(wv[0][j], hs, a0);
      a1 = fmaf(wv[1][j], hs, a1);
      a2 = fmaf(wv[2][j], hs, a2);
      a3 = fmaf(wv[3][j], hs, a3);
    }
    float (*Pb)[259] = P[t & 1];
    Pb[w][l]        = a0;
    Pb[w][64  | l]  = a1;
    Pb[w][128 | l]  = a2;
    Pb[w][192 | l]  = a3;
    __syncthreads();   // the only barrier per step (double-buffered P)

    // redundant reduce: quarter q sums chunks 4q..4q+3, butterfly across quarters
    float s = (Pb[(q << 2) + 0][hsel] + Pb[(q << 2) + 1][hsel])
            + (Pb[(q << 2) + 2][hsel] + Pb[(q << 2) + 3][hsel]);
    s += __shfl_xor(s, 16, 64);
    s += __shfl_xor(s, 32, 64);
    float z = x + s;
    // tanh(z) = 1 - 2/(exp2(2z*log2e)+1)
    float e2 = __builtin_amdgcn_exp2f(z * 2.885390081777927f);
    float hn = fmaf(-2.f, __builtin_amdgcn_rcpf(e2 + 1.f), 1.f);
    hreg = hn;
    if (q == 0) hall[rowbase + ((size_t)t << 8) + hsel] = (_Float16)hn;
  }
  if (q == 0) hfin[(b << 8) + hsel] = hreg;
}

// ---------- Kernel C: MFMA f16 GEMM, in place over d_out.
// Block: 64 rows, 512 threads (8 waves). Wave w owns n-tile v in [16w,16w+16),
// W_ho frags weight-stationary in VGPRs (32/lane). A-tile (64x256 f16, 32 KB)
// staged in LDS with ((row&7)<<4) XOR swizzle -> conflict-free ds_read_b128.
__global__ __launch_bounds__(512) void k_out(const float* __restrict__ W_ho,
    const float* __restrict__ b_ho, float* out_base) {
  __shared__ _Float16 Atile[64 * 256];  // 32 KB
  const int tid = threadIdx.x;
  const int l = tid & 63;
  const int w = tid >> 6;
  const size_t m0 = (size_t)blockIdx.x * 64;
  const _Float16* hall = (const _Float16*)out_base;

  // stage A tile (reads the f16 overlay BEFORE any output write; barrier protects)
  {
    const uint4* src = (const uint4*)(hall + (m0 << 8));
    #pragma unroll
    for (int i = 0; i < 4; ++i) {
      int g = tid + (i << 9);            // 2048 x 16B = 32 KB
      int row = g >> 5;                  // 32 x 16B per row
      int cb = (g & 31) << 4;            // byte col
      uint4 d = src[g];
      *(uint4*)((char*)Atile + row * 512 + (cb ^ ((row & 7) << 4))) = d;
    }
  }

  // B frags: Bf[ks] holds W_ho[v = 16w + (l&15)][k = 32ks + 8(l>>4) .. +8] as f16
  f16x8 Bf[8];
  {
    const int v = (w << 4) + (l & 15);
    const float* srcb = W_ho + v * Hn + ((l >> 4) << 3);
    #pragma unroll
    for (int ks = 0; ks < 8; ++ks) {
      float4 f0 = ((const float4*)(srcb + (ks << 5)))[0];
      float4 f1 = ((const float4*)(srcb + (ks << 5)))[1];
      union { _Float16 h[8]; f16x8 v8; } u;
      u.h[0] = (_Float16)f0.x; u.h[1] = (_Float16)f0.y; u.h[2] = (_Float16)f0.z; u.h[3] = (_Float16)f0.w;
      u.h[4] = (_Float16)f1.x; u.h[5] = (_Float16)f1.y; u.h[6] = (_Float16)f1.z; u.h[7] = (_Float16)f1.w;
      Bf[ks] = u.v8;
    }
  }
  const float bias = b_ho[(w << 4) + (l & 15)];
  __syncthreads();

  #pragma unroll
  for (int mt = 0; mt < 4; ++mt) {
    f32x4 acc = {bias, bias, bias, bias};
    const int row = (mt << 4) + (l & 15);
    #pragma unroll
    for (int ks = 0; ks < 8; ++ks) {
      int cb = ((ks << 5) + ((l >> 4) << 3)) << 1;  // byte col = k*2
      f16x8 a = *(const f16x8*)((const char*)Atile + row * 512 + (cb ^ ((row & 7) << 4)));
      acc = __builtin_amdgcn_mfma_f32_16x16x32_f16(a, Bf[ks], acc, 0, 0, 0);
    }
    // D: col = lane&15 (v), row = (lane>>4)*4 + reg (m)
    float* orow = out_base + (m0 + (mt << 4) + ((l >> 4) << 2)) * Vn + (w << 4) + (l & 15);
    orow[0]       = acc[0];
    orow[Vn]      = acc[1];
    orow[2 * Vn]  = acc[2];
    orow[3 * Vn]  = acc[3];
  }
}

extern "C" void kernel_launch(void* const* d_in, const int* in_sizes, int n_in,
                              void* d_out, int out_size, void* d_ws, size_t ws_size,
                              hipStream_t stream) {
  (void)in_sizes; (void)n_in; (void)out_size;
  const int*   inp    = (const int*)  d_in[0];
  const float* hidden = (const float*)d_in[1];
  const float* emb    = (const float*)d_in[2];
  const float* W_ih   = (const float*)d_in[3];
  const float* b_ih   = (const float*)d_in[4];
  const float* W_hh   = (const float*)d_in[5];
  const float* b_hh   = (const float*)d_in[6];
  const float* W_ho   = (const float*)d_in[7];
  const float* b_ho   = (const float*)d_in[8];
  float* out = (float*)d_out;

  float* T2 = (ws_size >= (size_t)(Vn * Hn * sizeof(float))) ? (float*)d_ws
            : out + (size_t)Bn * Sn * Vn;

  k_table<<<dim3(Vn), dim3(Hn), 0, stream>>>(emb, W_ih, b_ih, b_hh, T2);
  k_rnn<<<dim3(Bn), dim3(1024), 0, stream>>>(inp, hidden, W_hh, T2, out);
  k_out<<<dim3((Bn * Sn) / 64), dim3(512), 0, stream>>>(W_ho, b_ho, out);
}